// Round 1
// baseline (14811.226 us; speedup 1.0000x reference)
//
#include <hip/hip_runtime.h>
#include <hip/hip_bf16.h>
#include <stdint.h>
#include <stddef.h>

// Problem dims
#define SEQ   2048
#define BATCH 32
#define HID   512
#define G4    2048   // 4*HID
#define NSL   64     // workgroups (slices) per direction
#define UPS   8      // hidden units per slice (NSL*UPS == HID)

typedef __bf16 bf16;
typedef bf16  bf16x8 __attribute__((ext_vector_type(8)));
typedef float f32x4  __attribute__((ext_vector_type(4)));

// ---------------------------------------------------------------------------
// Prep 1: embedding gather -> bf16 [S*B][H]; h0 -> hbuf slot 0 (slice-major)
// hbuf layout: [t][slice][b][u] bf16, slot stride = BATCH*HID = 16384 elems
// ---------------------------------------------------------------------------
__global__ void k_embed(const int* __restrict__ tokens,
                        const float* __restrict__ h0,
                        const float* __restrict__ table,
                        bf16* __restrict__ embT,
                        bf16* __restrict__ hbuf_f,
                        bf16* __restrict__ hbuf_b)
{
    int wid  = (blockIdx.x * blockDim.x + threadIdx.x) >> 6;
    int lane = threadIdx.x & 63;
    int k = lane * 8;                      // 64 lanes * 8 = 512 = HID
    if (wid < SEQ * BATCH) {
        int tok = tokens[wid];
        const float* src = table + (size_t)tok * HID;
        float4 a = *(const float4*)(src + k);
        float4 b = *(const float4*)(src + k + 4);
        bf16x8 v;
        v[0]=(bf16)a.x; v[1]=(bf16)a.y; v[2]=(bf16)a.z; v[3]=(bf16)a.w;
        v[4]=(bf16)b.x; v[5]=(bf16)b.y; v[6]=(bf16)b.z; v[7]=(bf16)b.w;
        *(bf16x8*)(embT + (size_t)wid * HID + k) = v;
    } else if (wid < SEQ * BATCH + BATCH) {
        int b = wid - SEQ * BATCH;
        const float* src = h0 + (size_t)b * HID;
        bf16x8 v;
        #pragma unroll
        for (int j = 0; j < 8; j++) v[j] = (bf16)src[k + j];
        // slot 0, slice = lane, units 0..7: offset = lane*256 + b*8
        *(bf16x8*)(hbuf_f + lane * (BATCH * UPS) + b * UPS) = v;
        *(bf16x8*)(hbuf_b + lane * (BATCH * UPS) + b * UPS) = v;
    }
}

// ---------------------------------------------------------------------------
// Prep 2: transpose+convert weights: [HID][G4] fp32 -> [G4][HID] bf16
// ---------------------------------------------------------------------------
__global__ void k_transpose(const float* s0, const float* s1,
                            const float* s2, const float* s3,
                            bf16* __restrict__ dst)
{
    const float* srcs[4] = {s0, s1, s2, s3};
    const float* src = srcs[blockIdx.y];
    bf16* d = dst + (size_t)blockIdx.y * ((size_t)G4 * HID);
    int c = blockIdx.x * 256 + threadIdx.x;          // 8 blocks * 256 = 2048
    for (int k = 0; k < HID; k++)                    // coalesced reads over c
        d[(size_t)c * HID + k] = (bf16)src[(size_t)k * G4 + c];
}

// ---------------------------------------------------------------------------
// Persistent bidirectional LSTM recurrence.
// 128 wgs: dir = bid&1, slice = bid>>1 owns units [slice*8, slice*8+8).
// LDS: [0,32K)    whT slice, swizzled rows [32 cols][512 k] bf16
//      [32K,64K)  h_t staged, swizzled rows [32 b][512 k] bf16
//      [64K,68.5K) gbuf fp32 [32][36]   (separate region -> only 2 barriers/step)
// Sync: SENTINEL POLL. hbuf slots (write-once per t) are pre-filled with
// 0xFFFF (-NaN bf16, unreachable from finite math). Producers store h quads
// agent-scope; consumers load + retry quads still reading sentinel. No flags,
// no vmcnt(0) drain, no fences -> no hot-line LLC serialization.
// ---------------------------------------------------------------------------
__global__ __launch_bounds__(256, 1) void k_lstm(
    const bf16* __restrict__ embT,
    const bf16* __restrict__ wxT,    // [2][G4][HID] bf16
    const bf16* __restrict__ whT,    // [2][G4][HID] bf16
    const float* __restrict__ bx_f, const float* __restrict__ bh_f,
    const float* __restrict__ bx_b, const float* __restrict__ bh_b,
    const float* __restrict__ h0,
    bf16* __restrict__ hbuf_f, bf16* __restrict__ hbuf_b,
    float* __restrict__ out)
{
    __shared__ __align__(16) char smem[65536 + 4608];
    float* gbuf = (float*)(smem + 65536);   // [32][36] fp32, own region

    const int tid   = threadIdx.x;
    const int bid   = blockIdx.x;
    const int dir   = bid & 1;
    const int slice = bid >> 1;
    const int u0    = slice * UPS;

    const bf16* wxTs = wxT + (size_t)dir * ((size_t)G4 * HID);
    const bf16* whTs = whT + (size_t)dir * ((size_t)G4 * HID);
    const float* bx  = dir ? bx_b : bx_f;
    const float* bh  = dir ? bh_b : bh_f;
    bf16* hbuf       = dir ? hbuf_b : hbuf_f;

    // ---- load whT slice into LDS (swizzled: addr = row*1024 + (kb ^ ((row&7)<<4)))
    #pragma unroll
    for (int i = 0; i < 8; i++) {
        int e  = i * 2048 + tid * 8;       // elem in [0,16384)
        int lc = e >> 9;
        int k  = e & 511;                  // multiple of 8
        int c  = (lc >> 3) * HID + u0 + (lc & 7);
        bf16x8 v = *(const bf16x8*)(whTs + (size_t)c * HID + k);
        *(bf16x8*)(smem + lc * 1024 + ((k * 2) ^ ((lc & 7) << 4))) = v;
    }

    // wave/tile assignment: 4 waves = 2 M-tiles x 2 N-tiles of 16x16
    const int w     = tid >> 6;
    const int lane  = tid & 63;
    const int mtile = w >> 1;              // batch tile 0..1
    const int ntile = w & 1;               // col tile 0..1
    const int lrow  = lane & 15;
    const int lc_b  = ntile * 16 + lrow;                       // local col 0..31
    const int gcol  = (lc_b >> 3) * HID + u0 + (lc_b & 7);     // global gate col
    const float bias = bx[gcol] + bh[gcol];

    const int arow   = mtile * 16 + lrow;       // A rows (batch) 0..31
    const int brow_off = lc_b * 1024;
    const int bswz     = (lc_b & 7) << 4;
    const int arow_off = 32768 + arow * 1024;
    const int aswz     = (arow & 7) << 4;

    // staging decode (per thread): quad q = j*256+tid -> slice_s=j*4+w,
    // b=lane>>1, u=(lane&1)*4;  LDS row sb, column byte j*64+scol0
    const int sb    = lane >> 1;                 // staging LDS row (batch)
    const int scol0 = w * 16 + (lane & 1) * 8;   // column byte base (j adds j*64)
    const int sswz  = (sb & 7) << 4;

    // pointwise: wave 0 only, 4 units per thread
    const int pb = lane >> 1;              // batch 0..31
    const int pu = (lane & 1) * 4;         // unit group {0,4}
    f32x4 creg = {0.f, 0.f, 0.f, 0.f};
    if (tid < 64)
        creg = *(const f32x4*)(h0 + (size_t)pb * HID + u0 + pu);

    __syncthreads();

    for (int t = 0; t < SEQ; t++) {
        const int s = dir ? (SEQ - 1 - t) : t;

        // ---- phase X: acc = bias + emb[s] @ wx_slice (cached loads) ----
        // (done before the h_t poll so producer stores have time to land)
        f32x4 acc = {bias, bias, bias, bias};
        const bf16* aX = embT + ((size_t)s * BATCH + arow) * HID + ((lane >> 4) * 8);
        const bf16* bX = wxTs + (size_t)gcol * HID + ((lane >> 4) * 8);
        #pragma unroll
        for (int kk = 0; kk < 16; kk++) {
            bf16x8 a = *(const bf16x8*)(aX + kk * 32);
            bf16x8 b = *(const bf16x8*)(bX + kk * 32);
            acc = __builtin_amdgcn_mfma_f32_16x16x32_bf16(a, b, acc, 0, 0, 0);
        }

        // ---- stage h_t: sentinel-poll agent-scope loads, retry pending only ----
        {
            const unsigned long long* hsrc = (const unsigned long long*)
                ((const char*)hbuf + (size_t)t * (BATCH * HID) * 2);
            unsigned long long hv[16];
            unsigned pend = 0xFFFFu;
            int rounds = 0;
            uint64_t t0c = 0;
            for (;;) {
                #pragma unroll
                for (int jj = 0; jj < 16; jj++) {
                    int j = (jj + bid) & 15;       // stagger line bursts by wg
                    if ((pend >> j) & 1)
                        hv[j] = __hip_atomic_load(hsrc + (size_t)j * 256 + tid,
                                                  __ATOMIC_RELAXED,
                                                  __HIP_MEMORY_SCOPE_AGENT);
                }
                unsigned np = 0;
                #pragma unroll
                for (int j = 0; j < 16; j++) {
                    // check one bf16 per 4B dword (dword stores are atomic)
                    bool bad = ((pend >> j) & 1) &&
                               ((((unsigned)hv[j] & 0xFFFFu) == 0xFFFFu) ||
                                (((unsigned)(hv[j] >> 32) & 0xFFFFu) == 0xFFFFu));
                    np |= bad ? (1u << j) : 0u;
                }
                pend = np;
                if (__all(pend == 0)) break;
                if (!(++rounds & 255)) {           // hang safety ~20ms
                    uint64_t now = __builtin_amdgcn_s_memrealtime();
                    if (!t0c) t0c = now;
                    else if (now - t0c > 2000000ULL) break;
                }
            }
            #pragma unroll
            for (int j = 0; j < 16; j++)
                *(unsigned long long*)(smem + 32768 + sb * 1024 +
                                       ((j * 64 + scol0) ^ sswz)) = hv[j];
        }
        __syncthreads();   // bar A: staging visible to all waves

        // ---- phase H: acc += h_t @ wh_slice (LDS) ----
        #pragma unroll
        for (int kk = 0; kk < 16; kk++) {
            int kb = kk * 64 + ((lane >> 4) << 4);
            bf16x8 a = *(const bf16x8*)(smem + arow_off + (kb ^ aswz));
            bf16x8 b = *(const bf16x8*)(smem + brow_off + (kb ^ bswz));
            acc = __builtin_amdgcn_mfma_f32_16x16x32_bf16(a, b, acc, 0, 0, 0);
        }

        // ---- gates -> gbuf (C/D layout: col = lane&15, row = (lane>>4)*4+r) ----
        {
            int r0 = mtile * 16 + (lane >> 4) * 4;
            #pragma unroll
            for (int r = 0; r < 4; r++)
                gbuf[(r0 + r) * 36 + lc_b] = acc[r];
        }
        __syncthreads();   // bar B: gbuf ready; also orders phaseH reads
                           // before next iteration's staging overwrites

        // ---- pointwise LSTM cell: wave 0, 4 units/thread ----
        if (tid < 64) {
            f32x4 gi = *(const f32x4*)(gbuf + pb * 36 + pu);
            f32x4 gf = *(const f32x4*)(gbuf + pb * 36 + 8 + pu);
            f32x4 gg = *(const f32x4*)(gbuf + pb * 36 + 16 + pu);
            f32x4 go = *(const f32x4*)(gbuf + pb * 36 + 24 + pu);
            float hv[4];
            #pragma unroll
            for (int j = 0; j < 4; j++) {
                float si = 1.f / (1.f + __expf(-gi[j]));
                float sf = 1.f / (1.f + __expf(-gf[j]));
                float so = 1.f / (1.f + __expf(-go[j]));
                float e2 = __expf(2.f * gg[j]);
                float tg = (e2 - 1.f) / (e2 + 1.f);
                creg[j] = sf * creg[j] + si * tg;
                float ec = __expf(2.f * creg[j]);
                float tc = (ec - 1.f) / (ec + 1.f);
                hv[j] = so * tc;
            }
            // pack 4 bf16 -> one 8B agent-scope store; the data IS the flag
            union { bf16 h[4]; unsigned long long q; } pk;
            #pragma unroll
            for (int j = 0; j < 4; j++) pk.h[j] = (bf16)hv[j];
            __hip_atomic_store(
                (unsigned long long*)(hbuf + (size_t)(t + 1) * (BATCH * HID)
                                      + slice * (BATCH * UPS) + pb * UPS + pu),
                pk.q, __ATOMIC_RELAXED, __HIP_MEMORY_SCOPE_AGENT);
            // out store — off the inter-wg critical path
            float4 ov = {hv[0], hv[1], hv[2], hv[3]};
            *(float4*)(out + (size_t)pb * ((size_t)SEQ * 2 * HID)
                       + (size_t)s * (2 * HID) + dir * HID + u0 + pu) = ov;
        }
        // no end barrier: bar A of next iteration orders gbuf reuse
    }
}

// ---------------------------------------------------------------------------
// Workspace layout (bytes):
//   embT   :         0 ..  67,108,864   bf16 [S*B][H]
//   hbuf_f :  67,108,864 .. 134,250,496  bf16 [S+1][64][32][8]
//   hbuf_b : 134,250,496 .. 201,392,128
//   wxT    : 201,392,128 .. 205,586,432  bf16 [2][G4][H]
//   whT    : 205,586,432 .. 209,780,736  bf16 [2][G4][H]
//   (hbufs are sentinel-filled 0xFF each launch: bf16 0xFFFF = -NaN,
//    unreachable from finite arithmetic -> safe readiness marker)
// ---------------------------------------------------------------------------
extern "C" void kernel_launch(void* const* d_in, const int* in_sizes, int n_in,
                              void* d_out, int out_size, void* d_ws, size_t ws_size,
                              hipStream_t stream)
{
    const int*   tokens = (const int*)  d_in[0];
    const float* h0     = (const float*)d_in[1];
    const float* table  = (const float*)d_in[2];
    const float* wx_f   = (const float*)d_in[3];
    const float* bx_f   = (const float*)d_in[4];
    const float* wh_f   = (const float*)d_in[5];
    const float* bh_f   = (const float*)d_in[6];
    const float* wx_b   = (const float*)d_in[7];
    const float* bx_b   = (const float*)d_in[8];
    const float* wh_b   = (const float*)d_in[9];
    const float* bh_b   = (const float*)d_in[10];
    float* out = (float*)d_out;
    char*  ws  = (char*)d_ws;

    const size_t OFF_EMBT  = 0;
    const size_t OFF_HF    = 67108864ULL;
    const size_t OFF_HB    = OFF_HF  + 67141632ULL;
    const size_t OFF_WXT   = OFF_HB  + 67141632ULL;
    const size_t OFF_WHT   = OFF_WXT + 4194304ULL;

    bf16* embT   = (bf16*)(ws + OFF_EMBT);
    bf16* hbuf_f = (bf16*)(ws + OFF_HF);
    bf16* hbuf_b = (bf16*)(ws + OFF_HB);
    bf16* wxT    = (bf16*)(ws + OFF_WXT);
    bf16* whT    = (bf16*)(ws + OFF_WHT);

    // sentinel-fill both hbufs (0xFFFF bf16 = -NaN); k_embed then writes slot 0
    hipMemsetAsync(ws + OFF_HF, 0xFF, 2ULL * 67141632ULL, stream);

    // embedding gather + h0 slot-0
    {
        int waves  = SEQ * BATCH + BATCH;
        int blocks = (waves * 64 + 255) / 256;
        k_embed<<<blocks, 256, 0, stream>>>(tokens, h0, table, embT, hbuf_f, hbuf_b);
    }
    // weight transposes: slots {wxT_f, wxT_b, whT_f, whT_b} contiguous
    k_transpose<<<dim3(8, 4), 256, 0, stream>>>(wx_f, wx_b, wh_f, wh_b, wxT);

    // persistent recurrence: 128 wgs (64 per direction), all co-resident
    k_lstm<<<128, 256, 0, stream>>>(embT, wxT, whT,
                                    bx_f, bh_f, bx_b, bh_b, h0,
                                    hbuf_f, hbuf_b, out);
}

// Round 2
// 11685.954 us; speedup vs baseline: 1.2674x; 1.2674x over previous
//
#include <hip/hip_runtime.h>
#include <hip/hip_bf16.h>
#include <stdint.h>
#include <stddef.h>

// Problem dims
#define SEQ   2048
#define BATCH 32
#define HID   512
#define G4    2048   // 4*HID
#define NSL   64     // workgroups (slices) per direction
#define UPS   8      // hidden units per slice (NSL*UPS == HID)

typedef __bf16 bf16;
typedef bf16  bf16x8 __attribute__((ext_vector_type(8)));
typedef float f32x4  __attribute__((ext_vector_type(4)));

// ---------------------------------------------------------------------------
// Prep 1: embedding gather -> bf16 [S*B][H]; h0 -> hbuf slot 0 (slice-major)
// hbuf layout: [t][slice][b][u] bf16, slot stride = BATCH*HID = 16384 elems
// ---------------------------------------------------------------------------
__global__ void k_embed(const int* __restrict__ tokens,
                        const float* __restrict__ h0,
                        const float* __restrict__ table,
                        bf16* __restrict__ embT,
                        bf16* __restrict__ hbuf_f,
                        bf16* __restrict__ hbuf_b)
{
    int wid  = (blockIdx.x * blockDim.x + threadIdx.x) >> 6;
    int lane = threadIdx.x & 63;
    int k = lane * 8;                      // 64 lanes * 8 = 512 = HID
    if (wid < SEQ * BATCH) {
        int tok = tokens[wid];
        const float* src = table + (size_t)tok * HID;
        float4 a = *(const float4*)(src + k);
        float4 b = *(const float4*)(src + k + 4);
        bf16x8 v;
        v[0]=(bf16)a.x; v[1]=(bf16)a.y; v[2]=(bf16)a.z; v[3]=(bf16)a.w;
        v[4]=(bf16)b.x; v[5]=(bf16)b.y; v[6]=(bf16)b.z; v[7]=(bf16)b.w;
        *(bf16x8*)(embT + (size_t)wid * HID + k) = v;
    } else if (wid < SEQ * BATCH + BATCH) {
        int b = wid - SEQ * BATCH;
        const float* src = h0 + (size_t)b * HID;
        bf16x8 v;
        #pragma unroll
        for (int j = 0; j < 8; j++) v[j] = (bf16)src[k + j];
        // slot 0, slice = lane, units 0..7: offset = lane*256 + b*8
        *(bf16x8*)(hbuf_f + lane * (BATCH * UPS) + b * UPS) = v;
        *(bf16x8*)(hbuf_b + lane * (BATCH * UPS) + b * UPS) = v;
    }
}

// ---------------------------------------------------------------------------
// Prep 2: transpose+convert weights: [HID][G4] fp32 -> [G4][HID] bf16
// ---------------------------------------------------------------------------
__global__ void k_transpose(const float* s0, const float* s1,
                            const float* s2, const float* s3,
                            bf16* __restrict__ dst)
{
    const float* srcs[4] = {s0, s1, s2, s3};
    const float* src = srcs[blockIdx.y];
    bf16* d = dst + (size_t)blockIdx.y * ((size_t)G4 * HID);
    int c = blockIdx.x * 256 + threadIdx.x;          // 8 blocks * 256 = 2048
    for (int k = 0; k < HID; k++)                    // coalesced reads over c
        d[(size_t)c * HID + k] = (bf16)src[(size_t)k * G4 + c];
}

// ---------------------------------------------------------------------------
// Persistent bidirectional LSTM recurrence.
// 128 wgs: dir = bid&1, slice = bid>>1 owns units [slice*8, slice*8+8).
// LDS: [0,32K)     whT slice, swizzled rows [32 cols][512 k] bf16
//      [32K,64K)   h_t staged, swizzled rows [32 b][512 k] bf16
//      [64K,68.5K) gbuf fp32 [32][36]
// Sync (hybrid): producers issue h stores then the flag store with NO
// vmcnt drain (flag races data).  A dedicated idle wave (wave 1) polls the
// 64 flags (256 B/round -> no LLC storm); after the gate, the bulk h load
// runs once and per-quad sentinel (0xFFFF = -NaN bf16, unreachable from
// finite math) catches the rare straggler store still in flight.
// ---------------------------------------------------------------------------
__global__ __launch_bounds__(256, 1) void k_lstm(
    const bf16* __restrict__ embT,
    const bf16* __restrict__ wxT,    // [2][G4][HID] bf16
    const bf16* __restrict__ whT,    // [2][G4][HID] bf16
    const float* __restrict__ bx_f, const float* __restrict__ bh_f,
    const float* __restrict__ bx_b, const float* __restrict__ bh_b,
    const float* __restrict__ h0,
    bf16* __restrict__ hbuf_f, bf16* __restrict__ hbuf_b,
    uint32_t* __restrict__ flags_f, uint32_t* __restrict__ flags_b,
    float* __restrict__ out)
{
    __shared__ __align__(16) char smem[65536 + 4608];
    float* gbuf = (float*)(smem + 65536);   // [32][36] fp32, own region

    const int tid   = threadIdx.x;
    const int bid   = blockIdx.x;
    const int dir   = bid & 1;
    const int slice = bid >> 1;
    const int u0    = slice * UPS;

    const bf16* wxTs = wxT + (size_t)dir * ((size_t)G4 * HID);
    const bf16* whTs = whT + (size_t)dir * ((size_t)G4 * HID);
    const float* bx  = dir ? bx_b : bx_f;
    const float* bh  = dir ? bh_b : bh_f;
    bf16* hbuf       = dir ? hbuf_b : hbuf_f;
    uint32_t* flags  = dir ? flags_b : flags_f;

    // ---- load whT slice into LDS (swizzled: addr = row*1024 + (kb ^ ((row&7)<<4)))
    #pragma unroll
    for (int i = 0; i < 8; i++) {
        int e  = i * 2048 + tid * 8;       // elem in [0,16384)
        int lc = e >> 9;
        int k  = e & 511;                  // multiple of 8
        int c  = (lc >> 3) * HID + u0 + (lc & 7);
        bf16x8 v = *(const bf16x8*)(whTs + (size_t)c * HID + k);
        *(bf16x8*)(smem + lc * 1024 + ((k * 2) ^ ((lc & 7) << 4))) = v;
    }

    // wave/tile assignment: 4 waves = 2 M-tiles x 2 N-tiles of 16x16
    const int w     = tid >> 6;
    const int lane  = tid & 63;
    const int mtile = w >> 1;              // batch tile 0..1
    const int ntile = w & 1;               // col tile 0..1
    const int lrow  = lane & 15;
    const int lc_b  = ntile * 16 + lrow;                       // local col 0..31
    const int gcol  = (lc_b >> 3) * HID + u0 + (lc_b & 7);     // global gate col
    const float bias = bx[gcol] + bh[gcol];

    const int arow   = mtile * 16 + lrow;       // A rows (batch) 0..31
    const int brow_off = lc_b * 1024;
    const int bswz     = (lc_b & 7) << 4;
    const int arow_off = 32768 + arow * 1024;
    const int aswz     = (arow & 7) << 4;

    // staging decode (per thread): quad q = j*256+tid -> LDS row sb,
    // column byte j*64+scol0
    const int sb    = lane >> 1;                 // staging LDS row (batch)
    const int scol0 = w * 16 + (lane & 1) * 8;   // column byte base (j adds j*64)
    const int sswz  = (sb & 7) << 4;

    // pointwise: wave 0 only, 4 units per thread
    const int pb = lane >> 1;              // batch 0..31
    const int pu = (lane & 1) * 4;         // unit group {0,4}
    f32x4 creg = {0.f, 0.f, 0.f, 0.f};
    if (tid < 64)
        creg = *(const f32x4*)(h0 + (size_t)pb * HID + u0 + pu);

    __syncthreads();

    for (int t = 0; t < SEQ; t++) {
        const int s = dir ? (SEQ - 1 - t) : t;

        // ---- phase X: acc = bias + emb[s] @ wx_slice (cached loads) ----
        f32x4 acc = {bias, bias, bias, bias};
        const bf16* aX = embT + ((size_t)s * BATCH + arow) * HID + ((lane >> 4) * 8);
        const bf16* bX = wxTs + (size_t)gcol * HID + ((lane >> 4) * 8);
        #pragma unroll
        for (int kk = 0; kk < 16; kk++) {
            bf16x8 a = *(const bf16x8*)(aX + kk * 32);
            bf16x8 b = *(const bf16x8*)(bX + kk * 32);
            acc = __builtin_amdgcn_mfma_f32_16x16x32_bf16(a, b, acc, 0, 0, 0);
        }

        // ---- gate: dedicated wave 1 polls the 64 flags; others park at bar P.
        // Wave 1 is idle while wave 0 runs pointwise+phaseX, so detection
        // happens the moment the slowest slice's flag lands.
        if (w == 1 && t > 0) {
            const uint32_t* fp = flags + lane;
            int rounds = 0;
            uint64_t t0c = 0;
            for (;;) {
                uint32_t v = __hip_atomic_load(fp, __ATOMIC_RELAXED,
                                               __HIP_MEMORY_SCOPE_AGENT);
                if (__all(v >= (uint32_t)t)) break;
                if (!(++rounds & 63)) {            // hang safety ~20ms
                    uint64_t now = __builtin_amdgcn_s_memrealtime();
                    if (!t0c) t0c = now;
                    else if (now - t0c > 2000000ULL) break;
                }
            }
        }
        __atomic_signal_fence(__ATOMIC_ACQUIRE);
        __syncthreads();   // bar P: flags observed -> h stores were issued

        // ---- stage h_t: one bulk agent-scope load; sentinel catches stragglers
        {
            const unsigned long long* hsrc = (const unsigned long long*)
                ((const char*)hbuf + (size_t)t * (BATCH * HID) * 2);
            unsigned long long hv[16];
            unsigned pend = 0xFFFFu;
            int rounds = 0;
            uint64_t t0c = 0;
            for (;;) {
                #pragma unroll
                for (int j = 0; j < 16; j++) {
                    if ((pend >> j) & 1)
                        hv[j] = __hip_atomic_load(hsrc + (size_t)j * 256 + tid,
                                                  __ATOMIC_RELAXED,
                                                  __HIP_MEMORY_SCOPE_AGENT);
                }
                unsigned np = 0;
                #pragma unroll
                for (int j = 0; j < 16; j++) {
                    // check one bf16 per 4B dword (dword stores are atomic)
                    bool bad = ((pend >> j) & 1) &&
                               ((((unsigned)hv[j] & 0xFFFFu) == 0xFFFFu) ||
                                (((unsigned)(hv[j] >> 32) & 0xFFFFu) == 0xFFFFu));
                    np |= bad ? (1u << j) : 0u;
                }
                pend = np;
                if (__all(pend == 0)) break;
                if (!(++rounds & 63)) {            // hang safety ~20ms
                    uint64_t now = __builtin_amdgcn_s_memrealtime();
                    if (!t0c) t0c = now;
                    else if (now - t0c > 2000000ULL) break;
                }
            }
            #pragma unroll
            for (int j = 0; j < 16; j++)
                *(unsigned long long*)(smem + 32768 + sb * 1024 +
                                       ((j * 64 + scol0) ^ sswz)) = hv[j];
        }
        __syncthreads();   // bar A: staging visible to all waves

        // ---- phase H: acc += h_t @ wh_slice (LDS) ----
        #pragma unroll
        for (int kk = 0; kk < 16; kk++) {
            int kb = kk * 64 + ((lane >> 4) << 4);
            bf16x8 a = *(const bf16x8*)(smem + arow_off + (kb ^ aswz));
            bf16x8 b = *(const bf16x8*)(smem + brow_off + (kb ^ bswz));
            acc = __builtin_amdgcn_mfma_f32_16x16x32_bf16(a, b, acc, 0, 0, 0);
        }

        // ---- gates -> gbuf (C/D layout: col = lane&15, row = (lane>>4)*4+r) ----
        {
            int r0 = mtile * 16 + (lane >> 4) * 4;
            #pragma unroll
            for (int r = 0; r < 4; r++)
                gbuf[(r0 + r) * 36 + lc_b] = acc[r];
        }
        __syncthreads();   // bar B: gbuf ready; phase-H LDS reads also done

        // ---- pointwise LSTM cell: wave 0, 4 units/thread ----
        if (tid < 64) {
            f32x4 gi = *(const f32x4*)(gbuf + pb * 36 + pu);
            f32x4 gf = *(const f32x4*)(gbuf + pb * 36 + 8 + pu);
            f32x4 gg = *(const f32x4*)(gbuf + pb * 36 + 16 + pu);
            f32x4 go = *(const f32x4*)(gbuf + pb * 36 + 24 + pu);
            float hv[4];
            #pragma unroll
            for (int j = 0; j < 4; j++) {
                float si = 1.f / (1.f + __expf(-gi[j]));
                float sf = 1.f / (1.f + __expf(-gf[j]));
                float so = 1.f / (1.f + __expf(-go[j]));
                float e2 = __expf(2.f * gg[j]);
                float tg = (e2 - 1.f) / (e2 + 1.f);
                creg[j] = sf * creg[j] + si * tg;
                float ec = __expf(2.f * creg[j]);
                float tc = (ec - 1.f) / (ec + 1.f);
                hv[j] = so * tc;
            }
            // pack 4 bf16 -> one 8B agent-scope store (data self-validates)
            union { bf16 h[4]; unsigned long long q; } pk;
            #pragma unroll
            for (int j = 0; j < 4; j++) pk.h[j] = (bf16)hv[j];
            __hip_atomic_store(
                (unsigned long long*)(hbuf + (size_t)(t + 1) * (BATCH * HID)
                                      + slice * (BATCH * UPS) + pb * UPS + pu),
                pk.q, __ATOMIC_RELAXED, __HIP_MEMORY_SCOPE_AGENT);
            // flag store: same wave, after all 64 lanes' h stores ISSUED.
            // NO vmcnt drain — flag races data; sentinel covers the race.
            __atomic_signal_fence(__ATOMIC_SEQ_CST);
            if (tid == 0)
                __hip_atomic_store(&flags[slice], (uint32_t)(t + 1),
                                   __ATOMIC_RELAXED, __HIP_MEMORY_SCOPE_AGENT);
            // out store AFTER flag — off the inter-wg critical path
            float4 ov = {hv[0], hv[1], hv[2], hv[3]};
            *(float4*)(out + (size_t)pb * ((size_t)SEQ * 2 * HID)
                       + (size_t)s * (2 * HID) + dir * HID + u0 + pu) = ov;
        }
        // no end barrier: next iteration's bar P orders gbuf reuse
    }
}

// ---------------------------------------------------------------------------
// Workspace layout (bytes):
//   embT   :         0 ..  67,108,864   bf16 [S*B][H]
//   hbuf_f :  67,108,864 .. 134,250,496  bf16 [S+1][64][32][8]
//   hbuf_b : 134,250,496 .. 201,392,128
//   wxT    : 201,392,128 .. 205,586,432  bf16 [2][G4][H]
//   whT    : 205,586,432 .. 209,780,736  bf16 [2][G4][H]
//   flags  : 209,780,736 .. +512         2 x 64 uint32 (zeroed per launch)
//   (hbufs are sentinel-filled 0xFF each launch: bf16 0xFFFF = -NaN,
//    unreachable from finite arithmetic -> safe readiness marker)
// ---------------------------------------------------------------------------
extern "C" void kernel_launch(void* const* d_in, const int* in_sizes, int n_in,
                              void* d_out, int out_size, void* d_ws, size_t ws_size,
                              hipStream_t stream)
{
    const int*   tokens = (const int*)  d_in[0];
    const float* h0     = (const float*)d_in[1];
    const float* table  = (const float*)d_in[2];
    const float* wx_f   = (const float*)d_in[3];
    const float* bx_f   = (const float*)d_in[4];
    const float* wh_f   = (const float*)d_in[5];
    const float* bh_f   = (const float*)d_in[6];
    const float* wx_b   = (const float*)d_in[7];
    const float* bx_b   = (const float*)d_in[8];
    const float* wh_b   = (const float*)d_in[9];
    const float* bh_b   = (const float*)d_in[10];
    float* out = (float*)d_out;
    char*  ws  = (char*)d_ws;

    const size_t OFF_EMBT  = 0;
    const size_t OFF_HF    = 67108864ULL;
    const size_t OFF_HB    = OFF_HF  + 67141632ULL;
    const size_t OFF_WXT   = OFF_HB  + 67141632ULL;
    const size_t OFF_WHT   = OFF_WXT + 4194304ULL;
    const size_t OFF_FLAGS = OFF_WHT + 4194304ULL;

    bf16* embT   = (bf16*)(ws + OFF_EMBT);
    bf16* hbuf_f = (bf16*)(ws + OFF_HF);
    bf16* hbuf_b = (bf16*)(ws + OFF_HB);
    bf16* wxT    = (bf16*)(ws + OFF_WXT);
    bf16* whT    = (bf16*)(ws + OFF_WHT);
    uint32_t* flags_f = (uint32_t*)(ws + OFF_FLAGS);
    uint32_t* flags_b = (uint32_t*)(ws + OFF_FLAGS + 256);

    // flags start at 0; hbufs sentinel-filled (bf16 0xFFFF = -NaN)
    hipMemsetAsync(ws + OFF_FLAGS, 0, 512, stream);
    hipMemsetAsync(ws + OFF_HF, 0xFF, 2ULL * 67141632ULL, stream);

    // embedding gather + h0 slot-0
    {
        int waves  = SEQ * BATCH + BATCH;
        int blocks = (waves * 64 + 255) / 256;
        k_embed<<<blocks, 256, 0, stream>>>(tokens, h0, table, embT, hbuf_f, hbuf_b);
    }
    // weight transposes: slots {wxT_f, wxT_b, whT_f, whT_b} contiguous
    k_transpose<<<dim3(8, 4), 256, 0, stream>>>(wx_f, wx_b, wh_f, wh_b, wxT);

    // persistent recurrence: 128 wgs (64 per direction), all co-resident
    k_lstm<<<128, 256, 0, stream>>>(embT, wxT, whT,
                                    bx_f, bh_f, bx_b, bh_b, h0,
                                    hbuf_f, hbuf_b, flags_f, flags_b, out);
}

// Round 4
// 9260.346 us; speedup vs baseline: 1.5994x; 1.2619x over previous
//
#include <hip/hip_runtime.h>
#include <hip/hip_bf16.h>
#include <stdint.h>
#include <stddef.h>

// Problem dims
#define SEQ   2048
#define BATCH 32
#define HID   512
#define G4    2048   // 4*HID
#define NSL   64     // workgroups (slices) per direction
#define UPS   8      // hidden units per slice (NSL*UPS == HID)
#define RING  8      // hbuf ring depth (slots stay LLC-hot)
#define FPAD  32     // flag padding: 32 dwords = 128B line per slice

typedef __bf16 bf16;
typedef bf16  bf16x8 __attribute__((ext_vector_type(8)));
typedef float f32x4  __attribute__((ext_vector_type(4)));

// ---------------------------------------------------------------------------
// Prep 1: embedding gather -> bf16 [S*B][H]; h0 -> hbuf ring slot 0
// hbuf layout: [slot][slice][b][u] bf16, slot stride = BATCH*HID = 16384 elems
// ---------------------------------------------------------------------------
__global__ void k_embed(const int* __restrict__ tokens,
                        const float* __restrict__ h0,
                        const float* __restrict__ table,
                        bf16* __restrict__ embT,
                        bf16* __restrict__ hbuf_f,
                        bf16* __restrict__ hbuf_b)
{
    int wid  = (blockIdx.x * blockDim.x + threadIdx.x) >> 6;
    int lane = threadIdx.x & 63;
    int k = lane * 8;                      // 64 lanes * 8 = 512 = HID
    if (wid < SEQ * BATCH) {
        int tok = tokens[wid];
        const float* src = table + (size_t)tok * HID;
        float4 a = *(const float4*)(src + k);
        float4 b = *(const float4*)(src + k + 4);
        bf16x8 v;
        v[0]=(bf16)a.x; v[1]=(bf16)a.y; v[2]=(bf16)a.z; v[3]=(bf16)a.w;
        v[4]=(bf16)b.x; v[5]=(bf16)b.y; v[6]=(bf16)b.z; v[7]=(bf16)b.w;
        *(bf16x8*)(embT + (size_t)wid * HID + k) = v;
    } else if (wid < SEQ * BATCH + BATCH) {
        int b = wid - SEQ * BATCH;
        const float* src = h0 + (size_t)b * HID;
        bf16x8 v;
        #pragma unroll
        for (int j = 0; j < 8; j++) v[j] = (bf16)src[k + j];
        // ring slot 0, slice = lane, units 0..7: offset = lane*256 + b*8
        *(bf16x8*)(hbuf_f + lane * (BATCH * UPS) + b * UPS) = v;
        *(bf16x8*)(hbuf_b + lane * (BATCH * UPS) + b * UPS) = v;
    }
}

// ---------------------------------------------------------------------------
// Prep 2: transpose+convert weights: [HID][G4] fp32 -> [G4][HID] bf16
// ---------------------------------------------------------------------------
__global__ void k_transpose(const float* s0, const float* s1,
                            const float* s2, const float* s3,
                            bf16* __restrict__ dst)
{
    const float* srcs[4] = {s0, s1, s2, s3};
    const float* src = srcs[blockIdx.y];
    bf16* d = dst + (size_t)blockIdx.y * ((size_t)G4 * HID);
    int c = blockIdx.x * 256 + threadIdx.x;          // 8 blocks * 256 = 2048
    for (int k = 0; k < HID; k++)                    // coalesced reads over c
        d[(size_t)c * HID + k] = (bf16)src[(size_t)k * G4 + c];
}

// ---------------------------------------------------------------------------
// Persistent bidirectional LSTM recurrence.
// 128 wgs: dir = bid&1, slice = bid>>1 owns units [slice*8, slice*8+8).
// LDS: [0,32K)     whT slice, swizzled rows [32 cols][512 k] bf16
//      [32K,64K)   h_t staged, swizzled rows [32 b][512 k] bf16
//      [64K,68.5K) gbuf fp32 [32][36]
// Sync: R0 semantics (h stores -> vmcnt(0) drain -> flag), but:
//  * hbuf is an 8-slot RING -> store lines perpetually LLC-hot (no HBM
//    write-allocate fetch on the producer critical path)
//  * flags are 128B-padded per slice -> no LLC line write-queueing
//  * out stores are nontemporal -> no LLC flush pressure
//  * only wave 1 polls (overlaps wave 0/2/3 phase X)
// ---------------------------------------------------------------------------
__global__ __launch_bounds__(256, 1) void k_lstm(
    const bf16* __restrict__ embT,
    const bf16* __restrict__ wxT,    // [2][G4][HID] bf16
    const bf16* __restrict__ whT,    // [2][G4][HID] bf16
    const float* __restrict__ bx_f, const float* __restrict__ bh_f,
    const float* __restrict__ bx_b, const float* __restrict__ bh_b,
    const float* __restrict__ h0,
    bf16* __restrict__ hbuf_f, bf16* __restrict__ hbuf_b,
    uint32_t* __restrict__ flags_f, uint32_t* __restrict__ flags_b,
    float* __restrict__ out)
{
    __shared__ __align__(16) char smem[65536 + 4608];
    float* gbuf = (float*)(smem + 65536);   // [32][36] fp32, own region

    const int tid   = threadIdx.x;
    const int bid   = blockIdx.x;
    const int dir   = bid & 1;
    const int slice = bid >> 1;
    const int u0    = slice * UPS;

    const bf16* wxTs = wxT + (size_t)dir * ((size_t)G4 * HID);
    const bf16* whTs = whT + (size_t)dir * ((size_t)G4 * HID);
    const float* bx  = dir ? bx_b : bx_f;
    const float* bh  = dir ? bh_b : bh_f;
    bf16* hbuf       = dir ? hbuf_b : hbuf_f;
    uint32_t* flags  = dir ? flags_b : flags_f;

    // ---- load whT slice into LDS (swizzled: addr = row*1024 + (kb ^ ((row&7)<<4)))
    #pragma unroll
    for (int i = 0; i < 8; i++) {
        int e  = i * 2048 + tid * 8;       // elem in [0,16384)
        int lc = e >> 9;
        int k  = e & 511;                  // multiple of 8
        int c  = (lc >> 3) * HID + u0 + (lc & 7);
        bf16x8 v = *(const bf16x8*)(whTs + (size_t)c * HID + k);
        *(bf16x8*)(smem + lc * 1024 + ((k * 2) ^ ((lc & 7) << 4))) = v;
    }

    // wave/tile assignment: 4 waves = 2 M-tiles x 2 N-tiles of 16x16
    const int w     = tid >> 6;
    const int lane  = tid & 63;
    const int mtile = w >> 1;              // batch tile 0..1
    const int ntile = w & 1;               // col tile 0..1
    const int lrow  = lane & 15;
    const int lc_b  = ntile * 16 + lrow;                       // local col 0..31
    const int gcol  = (lc_b >> 3) * HID + u0 + (lc_b & 7);     // global gate col
    const float bias = bx[gcol] + bh[gcol];

    const int arow   = mtile * 16 + lrow;       // A rows (batch) 0..31
    const int brow_off = lc_b * 1024;
    const int bswz     = (lc_b & 7) << 4;
    const int arow_off = 32768 + arow * 1024;
    const int aswz     = (arow & 7) << 4;

    // staging decode (per thread): quad q = j*256+tid -> LDS row sb,
    // column byte j*64+scol0
    const int sb    = lane >> 1;                 // staging LDS row (batch)
    const int scol0 = w * 16 + (lane & 1) * 8;   // column byte base (j adds j*64)
    const int sswz  = (sb & 7) << 4;

    // pointwise: wave 0 only, 4 units per thread
    const int pb = lane >> 1;              // batch 0..31
    const int pu = (lane & 1) * 4;         // unit group {0,4}
    f32x4 creg = {0.f, 0.f, 0.f, 0.f};
    if (tid < 64)
        creg = *(const f32x4*)(h0 + (size_t)pb * HID + u0 + pu);

    __syncthreads();

    for (int t = 0; t < SEQ; t++) {
        const int s = dir ? (SEQ - 1 - t) : t;

        // ---- phase X: acc = bias + emb[s] @ wx_slice (cached loads) ----
        f32x4 acc = {bias, bias, bias, bias};
        const bf16* aX = embT + ((size_t)s * BATCH + arow) * HID + ((lane >> 4) * 8);
        const bf16* bX = wxTs + (size_t)gcol * HID + ((lane >> 4) * 8);
        #pragma unroll
        for (int kk = 0; kk < 16; kk++) {
            bf16x8 a = *(const bf16x8*)(aX + kk * 32);
            bf16x8 b = *(const bf16x8*)(bX + kk * 32);
            acc = __builtin_amdgcn_mfma_f32_16x16x32_bf16(a, b, acc, 0, 0, 0);
        }

        // ---- gate: dedicated wave 1 polls the 64 padded flags ----
        if (w == 1 && t > 0) {
            const uint32_t* fp = flags + lane * FPAD;   // one line per slice
            int rounds = 0;
            uint64_t t0c = 0;
            for (;;) {
                uint32_t v = __hip_atomic_load(fp, __ATOMIC_RELAXED,
                                               __HIP_MEMORY_SCOPE_AGENT);
                if (__all(v >= (uint32_t)t)) break;
                if (!(++rounds & 63)) {            // hang safety ~20ms
                    uint64_t now = __builtin_amdgcn_s_memrealtime();
                    if (!t0c) t0c = now;
                    else if (now - t0c > 2000000ULL) break;
                }
            }
        }
        __atomic_signal_fence(__ATOMIC_ACQUIRE);
        __syncthreads();   // bar P: flags observed -> h data at LLC (drained)

        // ---- stage h_t from ring slot t&7 (one round; bid-staggered bursts)
        {
            const unsigned long long* hsrc = (const unsigned long long*)
                ((const char*)hbuf + (size_t)(t & (RING - 1)) * (BATCH * HID) * 2);
            unsigned long long hv[16];
            #pragma unroll
            for (int jj = 0; jj < 16; jj++) {
                int j = (jj + bid) & 15;           // stagger line bursts by wg
                hv[jj] = __hip_atomic_load(hsrc + (size_t)j * 256 + tid,
                                           __ATOMIC_RELAXED,
                                           __HIP_MEMORY_SCOPE_AGENT);
            }
            #pragma unroll
            for (int jj = 0; jj < 16; jj++) {
                int j = (jj + bid) & 15;
                *(unsigned long long*)(smem + 32768 + sb * 1024 +
                                       ((j * 64 + scol0) ^ sswz)) = hv[jj];
            }
        }
        __syncthreads();   // bar A: staging visible to all waves

        // ---- phase H: acc += h_t @ wh_slice (LDS) ----
        #pragma unroll
        for (int kk = 0; kk < 16; kk++) {
            int kb = kk * 64 + ((lane >> 4) << 4);
            bf16x8 a = *(const bf16x8*)(smem + arow_off + (kb ^ aswz));
            bf16x8 b = *(const bf16x8*)(smem + brow_off + (kb ^ bswz));
            acc = __builtin_amdgcn_mfma_f32_16x16x32_bf16(a, b, acc, 0, 0, 0);
        }

        // ---- gates -> gbuf (C/D layout: col = lane&15, row = (lane>>4)*4+r) ----
        {
            int r0 = mtile * 16 + (lane >> 4) * 4;
            #pragma unroll
            for (int r = 0; r < 4; r++)
                gbuf[(r0 + r) * 36 + lc_b] = acc[r];
        }
        __syncthreads();   // bar B: gbuf ready; phase-H LDS reads also done

        // ---- pointwise LSTM cell: wave 0, 4 units/thread ----
        if (tid < 64) {
            f32x4 gi = *(const f32x4*)(gbuf + pb * 36 + pu);
            f32x4 gf = *(const f32x4*)(gbuf + pb * 36 + 8 + pu);
            f32x4 gg = *(const f32x4*)(gbuf + pb * 36 + 16 + pu);
            f32x4 go = *(const f32x4*)(gbuf + pb * 36 + 24 + pu);
            float hv[4];
            #pragma unroll
            for (int j = 0; j < 4; j++) {
                float si = 1.f / (1.f + __expf(-gi[j]));
                float sf = 1.f / (1.f + __expf(-gf[j]));
                float so = 1.f / (1.f + __expf(-go[j]));
                float e2 = __expf(2.f * gg[j]);
                float tg = (e2 - 1.f) / (e2 + 1.f);
                creg[j] = sf * creg[j] + si * tg;
                float ec = __expf(2.f * creg[j]);
                float tc = (ec - 1.f) / (ec + 1.f);
                hv[j] = so * tc;
            }
            // pack 4 bf16 -> one 8B agent-scope store into ring slot (t+1)&7
            union { bf16 h[4]; unsigned long long q; } pk;
            #pragma unroll
            for (int j = 0; j < 4; j++) pk.h[j] = (bf16)hv[j];
            __hip_atomic_store(
                (unsigned long long*)(hbuf
                    + (size_t)((t + 1) & (RING - 1)) * (BATCH * HID)
                    + slice * (BATCH * UPS) + pb * UPS + pu),
                pk.q, __ATOMIC_RELAXED, __HIP_MEMORY_SCOPE_AGENT);
            __atomic_signal_fence(__ATOMIC_SEQ_CST);
            __builtin_amdgcn_s_waitcnt(0x0F70);   // vmcnt(0): h stores at LLC
            if (tid == 0)
                __hip_atomic_store(&flags[slice * FPAD], (uint32_t)(t + 1),
                                   __ATOMIC_RELAXED, __HIP_MEMORY_SCOPE_AGENT);
            // out store AFTER flag, nontemporal (keep LLC clean)
            f32x4 ov = {hv[0], hv[1], hv[2], hv[3]};
            __builtin_nontemporal_store(ov,
                (f32x4*)(out + (size_t)pb * ((size_t)SEQ * 2 * HID)
                         + (size_t)s * (2 * HID) + dir * HID + u0 + pu));
        }
        // no end barrier: next iteration's bar P orders gbuf reuse
    }
}

// ---------------------------------------------------------------------------
// Workspace layout (bytes):
//   embT   :         0 ..  67,108,864   bf16 [S*B][H]
//   hbuf_f :  67,108,864 .. +262,144    bf16 ring [8][64][32][8]
//   hbuf_b :  67,371,008 .. +262,144
//   wxT    :  67,633,152 .. +4,194,304  bf16 [2][G4][H]
//   whT    :  71,827,456 .. +4,194,304
//   flags  :  76,021,760 .. +16,384     2 x 64 x 128B padded (zeroed/launch)
// ---------------------------------------------------------------------------
extern "C" void kernel_launch(void* const* d_in, const int* in_sizes, int n_in,
                              void* d_out, int out_size, void* d_ws, size_t ws_size,
                              hipStream_t stream)
{
    const int*   tokens = (const int*)  d_in[0];
    const float* h0     = (const float*)d_in[1];
    const float* table  = (const float*)d_in[2];
    const float* wx_f   = (const float*)d_in[3];
    const float* bx_f   = (const float*)d_in[4];
    const float* wh_f   = (const float*)d_in[5];
    const float* bh_f   = (const float*)d_in[6];
    const float* wx_b   = (const float*)d_in[7];
    const float* bx_b   = (const float*)d_in[8];
    const float* wh_b   = (const float*)d_in[9];
    const float* bh_b   = (const float*)d_in[10];
    float* out = (float*)d_out;
    char*  ws  = (char*)d_ws;

    const size_t OFF_EMBT  = 0;
    const size_t OFF_HF    = 67108864ULL;
    const size_t OFF_HB    = OFF_HF  + 262144ULL;
    const size_t OFF_WXT   = OFF_HB  + 262144ULL;
    const size_t OFF_WHT   = OFF_WXT + 4194304ULL;
    const size_t OFF_FLAGS = OFF_WHT + 4194304ULL;

    bf16* embT   = (bf16*)(ws + OFF_EMBT);
    bf16* hbuf_f = (bf16*)(ws + OFF_HF);
    bf16* hbuf_b = (bf16*)(ws + OFF_HB);
    bf16* wxT    = (bf16*)(ws + OFF_WXT);
    bf16* whT    = (bf16*)(ws + OFF_WHT);
    uint32_t* flags_f = (uint32_t*)(ws + OFF_FLAGS);
    uint32_t* flags_b = (uint32_t*)(ws + OFF_FLAGS + 8192);

    // flags must start at 0 every launch (ws is poisoned)
    (void)hipMemsetAsync(ws + OFF_FLAGS, 0, 16384, stream);

    // embedding gather + h0 ring-slot-0
    {
        int waves  = SEQ * BATCH + BATCH;
        int blocks = (waves * 64 + 255) / 256;
        k_embed<<<blocks, 256, 0, stream>>>(tokens, h0, table, embT, hbuf_f, hbuf_b);
    }
    // weight transposes: slots {wxT_f, wxT_b, whT_f, whT_b} contiguous
    k_transpose<<<dim3(8, 4), 256, 0, stream>>>(wx_f, wx_b, wh_f, wh_b, wxT);

    // persistent recurrence: 128 wgs (64 per direction), all co-resident
    k_lstm<<<128, 256, 0, stream>>>(embT, wxT, whT,
                                    bx_f, bh_f, bx_b, bh_b, h0,
                                    hbuf_f, hbuf_b, flags_f, flags_b, out);
}